// Round 2
// baseline (563.872 us; speedup 1.0000x reference)
//
#include <hip/hip_runtime.h>
#include <math.h>

// DictNet: out = sparsity(C) + h2(class-pair mean dists) + h1(group mean dists)/beta
// Pipeline: init -> L=D*C -> yh = x - L@x (+row norms) -> class sort -> per-class
// Gram+dist sums -> group dists -> final scalar.

#define TB 256
#define BK 16

__global__ __launch_bounds__(TB) void k_init(float* sq, float* S, float* h1,
                                             int* cnt, int N) {
  int i = blockIdx.x * TB + threadIdx.x;
  if (i < N) sq[i] = 0.f;
  if (i < 7) { S[i] = 0.f; cnt[i] = 0; }
  if (i == 0) h1[0] = 0.f;
}

// L[t] = dot(D[t*F .. t*F+F), C)   (t over N*N)
__global__ __launch_bounds__(TB) void k_lhat(const float* __restrict__ D,
    const float* __restrict__ C, float* __restrict__ L, long long NN, int F) {
  long long t = (long long)blockIdx.x * TB + threadIdx.x;
  if (t >= NN) return;
  const float* p = D + t * (long long)F;
  float s = 0.f;
  int f = 0;
  for (; f + 1 < F; f += 2) {
    float2 v = *(const float2*)(p + f);  // 8B-aligned: t*F*4 = 56t
    s = fmaf(v.x, C[f], s);
    s = fmaf(v.y, C[f + 1], s);
  }
  if (f < F) s = fmaf(p[f], C[f], s);
  L[t] = s;
}

// yh = x - L @ x ; also accumulate sq[row] = |yh[row]|^2 via atomics.
// 64x64 tile, 256 threads, 4x4 microtile, BK=16.
__global__ __launch_bounds__(TB) void k_yhat(const float* __restrict__ L,
    const float* __restrict__ x, float* __restrict__ yh, float* __restrict__ sq,
    int N, int d) {
  __shared__ float As[BK][68];  // A transposed: As[k][row], pad 68
  __shared__ float Bs[BK][64];
  const int t = threadIdx.x;
  const int tx = t & 15, ty = t >> 4;
  const int row0 = blockIdx.y * 64, col0 = blockIdx.x * 64;
  const int lar = t >> 2, lak = (t & 3) * 4;   // A load: row lar, k lak..lak+3
  const int lbk = t >> 4, lbj = (t & 15) * 4;  // B load: k lbk, col lbj..lbj+3
  const int ar = row0 + lar;
  float acc[4][4] = {};
  for (int k0 = 0; k0 < N; k0 += BK) {
    float4 a = {0.f, 0.f, 0.f, 0.f};
    if (ar < N) {
      if (k0 + lak + 4 <= N) {
        a = *(const float4*)(L + (size_t)ar * N + k0 + lak);
      } else {
        float tmp[4] = {0.f, 0.f, 0.f, 0.f};
        for (int u = 0; u < 4; ++u)
          if (k0 + lak + u < N) tmp[u] = L[(size_t)ar * N + k0 + lak + u];
        a = make_float4(tmp[0], tmp[1], tmp[2], tmp[3]);
      }
    }
    float4 b = {0.f, 0.f, 0.f, 0.f};
    if (k0 + lbk < N) b = *(const float4*)(x + (size_t)(k0 + lbk) * d + col0 + lbj);
    __syncthreads();
    As[lak + 0][lar] = a.x; As[lak + 1][lar] = a.y;
    As[lak + 2][lar] = a.z; As[lak + 3][lar] = a.w;
    *(float4*)&Bs[lbk][lbj] = b;
    __syncthreads();
#pragma unroll
    for (int k = 0; k < BK; ++k) {
      float4 av = *(const float4*)&As[k][ty * 4];
      float4 bv = *(const float4*)&Bs[k][tx * 4];
      float aa[4] = {av.x, av.y, av.z, av.w};
      float bb[4] = {bv.x, bv.y, bv.z, bv.w};
#pragma unroll
      for (int i = 0; i < 4; ++i)
#pragma unroll
        for (int j = 0; j < 4; ++j)
          acc[i][j] = fmaf(aa[i], bb[j], acc[i][j]);
    }
  }
#pragma unroll
  for (int i = 0; i < 4; ++i) {
    int row = row0 + ty * 4 + i;
    if (row >= N) continue;
    float s = 0.f;
#pragma unroll
    for (int j = 0; j < 4; ++j) {
      int col = col0 + tx * 4 + j;
      float v = x[(size_t)row * d + col] - acc[i][j];
      yh[(size_t)row * d + col] = v;
      s = fmaf(v, v, s);
    }
    atomicAdd(&sq[row], s);
  }
}

__global__ __launch_bounds__(TB) void k_count(const int* __restrict__ y,
    const int* __restrict__ mask, int* cnt, int N) {
  int n = blockIdx.x * TB + threadIdx.x;
  if (n < N && mask[n] != 0) atomicAdd(&cnt[y[n]], 1);
}

__global__ void k_prefix(const int* __restrict__ cnt, int* start, int* cursor) {
  int s = 0;
  for (int c = 0; c < 7; ++c) { start[c] = s; cursor[c] = s; s += cnt[c]; }
  start[7] = s;
}

__global__ __launch_bounds__(TB) void k_scatter(const int* __restrict__ y,
    const int* __restrict__ mask, int* cursor, int* perm, int N) {
  int n = blockIdx.x * TB + threadIdx.x;
  if (n < N && mask[n] != 0) {
    int p = atomicAdd(&cursor[y[n]], 1);
    perm[p] = n;
  }
}

// yp[p,:] = yh[perm[p],:]; sqp[p] = sq[perm[p]]
__global__ __launch_bounds__(TB) void k_gather(const float* __restrict__ yh,
    const float* __restrict__ sq, const int* __restrict__ perm,
    const int* __restrict__ start, float* __restrict__ yp,
    float* __restrict__ sqp, int d) {
  int tid = blockIdx.x * TB + threadIdx.x;
  int p = tid / d, k = tid % d;
  if (p >= start[7]) return;
  int src = perm[p];
  yp[(size_t)p * d + k] = yh[(size_t)src * d + k];
  if (k == 0) sqp[p] = sq[src];
}

// Per-class Gram -> distances -> sum. Block-diagonal only; symmetry: bx<=by, x2 off-diag.
__global__ __launch_bounds__(TB) void k_class(const float* __restrict__ yp,
    const float* __restrict__ sqp, const int* __restrict__ start,
    const int* __restrict__ cnt, float* __restrict__ S, int d) {
  const int c = blockIdx.z;
  const int n = cnt[c];
  const int by = blockIdx.y, bx = blockIdx.x;
  if (bx > by) return;
  if (by * 64 >= n) return;  // bx*64 <= by*64 < n
  const float factor = (bx < by) ? 2.f : 1.f;
  const int base = start[c];
  __shared__ float As[BK][68];
  __shared__ float Bs2[BK][68];
  const int t = threadIdx.x;
  const int tx = t & 15, ty = t >> 4;
  const int lr = t >> 2, lk = (t & 3) * 4;
  const int arow = by * 64 + lr;
  const int brow = bx * 64 + lr;
  float acc[4][4] = {};
  for (int k0 = 0; k0 < d; k0 += BK) {
    float4 a = {0.f, 0.f, 0.f, 0.f}, b = {0.f, 0.f, 0.f, 0.f};
    if (arow < n) a = *(const float4*)(yp + (size_t)(base + arow) * d + k0 + lk);
    if (brow < n) b = *(const float4*)(yp + (size_t)(base + brow) * d + k0 + lk);
    __syncthreads();
    As[lk + 0][lr] = a.x; As[lk + 1][lr] = a.y;
    As[lk + 2][lr] = a.z; As[lk + 3][lr] = a.w;
    Bs2[lk + 0][lr] = b.x; Bs2[lk + 1][lr] = b.y;
    Bs2[lk + 2][lr] = b.z; Bs2[lk + 3][lr] = b.w;
    __syncthreads();
#pragma unroll
    for (int k = 0; k < BK; ++k) {
      float4 av = *(const float4*)&As[k][ty * 4];
      float4 bv = *(const float4*)&Bs2[k][tx * 4];
      float aa[4] = {av.x, av.y, av.z, av.w};
      float bb[4] = {bv.x, bv.y, bv.z, bv.w};
#pragma unroll
      for (int i = 0; i < 4; ++i)
#pragma unroll
        for (int j = 0; j < 4; ++j)
          acc[i][j] = fmaf(aa[i], bb[j], acc[i][j]);
    }
  }
  float sum = 0.f;
#pragma unroll
  for (int i = 0; i < 4; ++i) {
    int ri = by * 64 + ty * 4 + i;
    if (ri >= n) continue;
    float si = sqp[base + ri];
#pragma unroll
    for (int j = 0; j < 4; ++j) {
      int cj = bx * 64 + tx * 4 + j;
      if (cj >= n) continue;
      float d2 = si + sqp[base + cj] - 2.f * acc[i][j];
      d2 = fmaxf(d2, 0.f);
      sum += sqrtf(d2);
    }
  }
  __syncthreads();
  float* red = &As[0][0];
  red[t] = sum;
  __syncthreads();
  for (int s2 = 128; s2 > 0; s2 >>= 1) {
    if (t < s2) red[t] += red[t + s2];
    __syncthreads();
  }
  if (t == 0) atomicAdd(&S[c], factor * red[0]);
}

// One block per negative-sample group; pair p over g*g, 4 lanes split the dot.
__global__ __launch_bounds__(TB) void k_h1(const float* __restrict__ yh,
    const int* __restrict__ groups, float* __restrict__ h1, int g, int d) {
  const int grp = blockIdx.x;
  const int* gi = groups + grp * g;
  const int t = threadIdx.x;
  const int p = t >> 2, q = t & 3;
  const int npair = g * g;
  float d2 = 0.f;
  if (p < npair) {
    const float4* A = (const float4*)(yh + (size_t)gi[p / g] * d);
    const float4* B = (const float4*)(yh + (size_t)gi[p % g] * d);
    const int n4 = d / 4, per = n4 / 4;
    for (int k = q * per; k < (q + 1) * per; ++k) {
      float4 a = A[k], b = B[k];
      float dx = a.x - b.x, dy = a.y - b.y, dz = a.z - b.z, dw = a.w - b.w;
      d2 += dx * dx + dy * dy + dz * dz + dw * dw;
    }
  }
  d2 += __shfl_down(d2, 2, 4);
  d2 += __shfl_down(d2, 1, 4);
  float v = (q == 0 && p < npair) ? sqrtf(d2) : 0.f;
  __shared__ float red[TB];
  red[t] = v;
  __syncthreads();
  for (int s = 128; s > 0; s >>= 1) {
    if (t < s) red[t] += red[t + s];
    __syncthreads();
  }
  if (t == 0) atomicAdd(h1, red[0] / (float)npair);
}

__global__ void k_final(const float* __restrict__ C, int F,
    const float* __restrict__ S, const int* __restrict__ cnt,
    const float* __restrict__ h1, float* __restrict__ out, float beta) {
  float l1 = 0.f, l2 = 0.f;
  for (int f = 0; f < F; ++f) { float v = C[f]; l1 += fabsf(v); l2 += v * v; }
  l2 = sqrtf(l2);
  float dims = sqrtf((float)F);
  float sp = (dims - l1 / l2) / (dims - 1.f);
  float h2 = 0.f;
  for (int c = 0; c < 7; ++c) {
    if (cnt[c] > 0) { float cc = (float)cnt[c]; h2 += S[c] / (cc * cc); }
  }
  out[0] = sp + h2 - h1[0] / beta;
}

extern "C" void kernel_launch(void* const* d_in, const int* in_sizes, int n_in,
                              void* d_out, int out_size, void* d_ws, size_t ws_size,
                              hipStream_t stream) {
  const float* D = (const float*)d_in[0];
  const float* C = (const float*)d_in[1];
  const float* x = (const float*)d_in[2];
  const int* y = (const int*)d_in[3];
  const int* mask = (const int*)d_in[4];  // bool arrives widened to int32
  const int* groups = (const int*)d_in[5];
  float* out = (float*)d_out;

  const int N = in_sizes[3];            // 3000
  const int F = in_sizes[1];            // 14
  const int d = in_sizes[2] / N;        // 512
  const int G = in_sizes[5] / 7;        // 200 groups of g=7
  const long long NN = (long long)N * N;

  // workspace layout (floats)
  float* ws = (float*)d_ws;
  float* L   = ws;                          // N*N
  float* yh  = L + NN;                      // N*d
  float* yp  = yh + (size_t)N * d;          // N*d
  float* sq  = yp + (size_t)N * d;          // N
  float* sqp = sq + N;                      // N
  float* S   = sqp + N;                     // 7
  float* h1  = S + 7;                       // 1 (+pad)
  int* perm   = (int*)(h1 + 9);             // N
  int* cnt    = perm + N;                   // 7
  int* start  = cnt + 7;                    // 8
  int* cursor = start + 8;                  // 7

  k_init<<<dim3((N + TB - 1) / TB), TB, 0, stream>>>(sq, S, h1, cnt, N);
  k_lhat<<<dim3((unsigned)((NN + TB - 1) / TB)), TB, 0, stream>>>(D, C, L, NN, F);
  k_yhat<<<dim3(d / 64, (N + 63) / 64), TB, 0, stream>>>(L, x, yh, sq, N, d);
  k_count<<<dim3((N + TB - 1) / TB), TB, 0, stream>>>(y, mask, cnt, N);
  k_prefix<<<1, 1, 0, stream>>>(cnt, start, cursor);
  k_scatter<<<dim3((N + TB - 1) / TB), TB, 0, stream>>>(y, mask, cursor, perm, N);
  k_gather<<<dim3((unsigned)(((size_t)N * d + TB - 1) / TB)), TB, 0, stream>>>(
      yh, sq, perm, start, yp, sqp, d);
  k_class<<<dim3((N + 63) / 64, (N + 63) / 64, 7), TB, 0, stream>>>(
      yp, sqp, start, cnt, S, d);
  k_h1<<<dim3(G), TB, 0, stream>>>(yh, groups, h1, 7, d);
  k_final<<<1, 1, 0, stream>>>(C, F, S, cnt, h1, out, (float)G / 7.0f);
}

// Round 3
// 335.582 us; speedup vs baseline: 1.6803x; 1.6803x over previous
//
#include <hip/hip_runtime.h>
#include <math.h>

// DictNet: out = sparsity(C) + h2(class-pair mean dists) + h1(group mean dists)/beta
// Pipeline: init -> Lbf=bf16(D*C) -> xT=bf16(x^T) -> yh = x - L@x (MFMA) -> sq ->
// class sort -> per-class Gram+dist sums -> group dists -> final scalar.

#define TB 256
#define BK 16

using short8 = __attribute__((ext_vector_type(8))) short;
using f32x4  = __attribute__((ext_vector_type(4))) float;

__device__ inline short f2bf(float f) {
  union { float f; unsigned u; } v; v.f = f;
  unsigned r = v.u + 0x7FFF + ((v.u >> 16) & 1);  // RNE
  return (short)(r >> 16);
}

__global__ __launch_bounds__(TB) void k_init(float* S, float* h1, int* cnt) {
  int i = threadIdx.x;
  if (i < 7) { S[i] = 0.f; cnt[i] = 0; }
  if (i == 0) h1[0] = 0.f;
}

// Lb[row][col] = bf16(dot(D[row,col,:], C)), stride Kp, pad cols zeroed.
__global__ __launch_bounds__(TB) void k_lhat(const float* __restrict__ D,
    const float* __restrict__ C, short* __restrict__ Lb, int N, int Kp, int F) {
  int row = blockIdx.y;
  int col = blockIdx.x * TB + threadIdx.x;
  if (col >= Kp) return;
  float s = 0.f;
  if (col < N) {
    const float* p = D + ((size_t)row * N + col) * F;
    int f = 0;
    for (; f + 1 < F; f += 2) {
      float2 v = *(const float2*)(p + f);  // 8B-aligned: offset 56*t
      s = fmaf(v.x, C[f], s);
      s = fmaf(v.y, C[f + 1], s);
    }
    if (f < F) s = fmaf(p[f], C[f], s);
  }
  Lb[(size_t)row * Kp + col] = f2bf(s);
}

// xT[n][k] = bf16(x[k][n]); k-pad (k>=N) zeroed. Block (32,8), 32x32 tiles.
__global__ __launch_bounds__(TB) void k_xT(const float* __restrict__ x,
    short* __restrict__ xT, int N, int d, int Kp) {
  __shared__ float tile[32][33];
  const int tx = threadIdx.x, ty = threadIdx.y;
  const int r0 = blockIdx.y * 32, c0 = blockIdx.x * 32;
#pragma unroll
  for (int i = 0; i < 4; ++i) {
    int r = r0 + ty + i * 8;
    tile[ty + i * 8][tx] = (r < N) ? x[(size_t)r * d + c0 + tx] : 0.f;
  }
  __syncthreads();
#pragma unroll
  for (int i = 0; i < 4; ++i) {
    int c = c0 + ty + i * 8;  // output row (n)
    xT[(size_t)c * Kp + r0 + tx] = f2bf(tile[tx][ty + i * 8]);
  }
}

// yh = x - Lb @ x  via bf16 MFMA. 64x64 tile, 4 waves (2x2), each wave 32x32
// (2x2 frags of 16x16x32). LDS stride 40 shorts (80B) to break bank conflicts.
__global__ __launch_bounds__(TB) void k_yhat_mfma(
    const short* __restrict__ Lb, const short* __restrict__ xT,
    const float* __restrict__ x, float* __restrict__ yh,
    int N, int d, int Kp) {
  __shared__ short As[64][40];
  __shared__ short Bs[64][40];
  // XCD-bijective swizzle (m204): consecutive work-ids per XCD -> A-panel L2 reuse
  const int nwg = gridDim.x;
  const int q = nwg >> 3, r = nwg & 7;
  const int xcd = blockIdx.x & 7, pos = blockIdx.x >> 3;
  const int wg = (xcd < r) ? xcd * (q + 1) + pos
                           : r * (q + 1) + (xcd - r) * q + pos;
  const int NCB = d >> 6;                 // col blocks (8)
  const int row0 = (wg / NCB) * 64, col0 = (wg % NCB) * 64;

  const int t = threadIdx.x;
  const int wid = t >> 6, lane = t & 63;
  const int wr = wid >> 1, wc = wid & 1;  // wave 2x2 over the 64x64 tile
  const int srow = t >> 2, skc = (t & 3) * 8;  // staging: row 0..63, k-chunk
  const int fr = lane & 15, fq = lane >> 4;    // fragment row/col, k-quarter

  const int grow = row0 + srow;
  const bool arow_ok = grow < N;
  const short* Lp = Lb + (size_t)grow * Kp + skc;
  const short* xp = xT + (size_t)(col0 + srow) * Kp + skc;

  f32x4 acc[2][2] = {};
  for (int k0 = 0; k0 < Kp; k0 += 32) {
    short8 a = {0, 0, 0, 0, 0, 0, 0, 0};
    if (arow_ok) a = *(const short8*)(Lp + k0);
    short8 b = *(const short8*)(xp + k0);
    __syncthreads();
    *(short8*)&As[srow][skc] = a;
    *(short8*)&Bs[srow][skc] = b;
    __syncthreads();
    short8 af[2], bf[2];
    af[0] = *(const short8*)&As[wr * 32 + fr][fq * 8];
    af[1] = *(const short8*)&As[wr * 32 + 16 + fr][fq * 8];
    bf[0] = *(const short8*)&Bs[wc * 32 + fr][fq * 8];
    bf[1] = *(const short8*)&Bs[wc * 32 + 16 + fr][fq * 8];
#pragma unroll
    for (int mi = 0; mi < 2; ++mi)
#pragma unroll
      for (int ni = 0; ni < 2; ++ni)
        acc[mi][ni] = __builtin_amdgcn_mfma_f32_16x16x32_bf16(
            af[mi], bf[ni], acc[mi][ni], 0, 0, 0);
  }
  // D layout: col = lane&15, row = (lane>>4)*4 + j
#pragma unroll
  for (int mi = 0; mi < 2; ++mi) {
#pragma unroll
    for (int j = 0; j < 4; ++j) {
      int m = row0 + wr * 32 + mi * 16 + fq * 4 + j;
      if (m >= N) continue;
#pragma unroll
      for (int ni = 0; ni < 2; ++ni) {
        int n = col0 + wc * 32 + ni * 16 + fr;
        float v = x[(size_t)m * d + n] - acc[mi][ni][j];
        yh[(size_t)m * d + n] = v;
      }
    }
  }
}

// sq[row] = |yh[row]|^2 ; one wave per row, d=512 -> 2x float4 per lane.
__global__ __launch_bounds__(TB) void k_sq(const float* __restrict__ yh,
    float* __restrict__ sq, int N, int d) {
  int row = blockIdx.x * 4 + (threadIdx.x >> 6);
  if (row >= N) return;
  int lane = threadIdx.x & 63;
  const float4* p = (const float4*)(yh + (size_t)row * d);
  float4 v1 = p[lane], v2 = p[lane + 64];
  float s = v1.x * v1.x + v1.y * v1.y + v1.z * v1.z + v1.w * v1.w
          + v2.x * v2.x + v2.y * v2.y + v2.z * v2.z + v2.w * v2.w;
#pragma unroll
  for (int off = 32; off > 0; off >>= 1) s += __shfl_down(s, off);
  if (lane == 0) sq[row] = s;
}

__global__ __launch_bounds__(TB) void k_count(const int* __restrict__ y,
    const int* __restrict__ mask, int* cnt, int N) {
  int n = blockIdx.x * TB + threadIdx.x;
  if (n < N && mask[n] != 0) atomicAdd(&cnt[y[n]], 1);
}

__global__ void k_prefix(const int* __restrict__ cnt, int* start, int* cursor) {
  int s = 0;
  for (int c = 0; c < 7; ++c) { start[c] = s; cursor[c] = s; s += cnt[c]; }
  start[7] = s;
}

__global__ __launch_bounds__(TB) void k_scatter(const int* __restrict__ y,
    const int* __restrict__ mask, int* cursor, int* perm, int N) {
  int n = blockIdx.x * TB + threadIdx.x;
  if (n < N && mask[n] != 0) {
    int p = atomicAdd(&cursor[y[n]], 1);
    perm[p] = n;
  }
}

// yp[p,:] = yh[perm[p],:]; sqp[p] = sq[perm[p]]
__global__ __launch_bounds__(TB) void k_gather(const float* __restrict__ yh,
    const float* __restrict__ sq, const int* __restrict__ perm,
    const int* __restrict__ start, float* __restrict__ yp,
    float* __restrict__ sqp, int d) {
  int tid = blockIdx.x * TB + threadIdx.x;
  int p = tid / d, k = tid % d;
  if (p >= start[7]) return;
  int src = perm[p];
  yp[(size_t)p * d + k] = yh[(size_t)src * d + k];
  if (k == 0) sqp[p] = sq[src];
}

// Per-class Gram -> distances -> sum. Block-diagonal only; symmetry: bx<=by, x2 off-diag.
__global__ __launch_bounds__(TB) void k_class(const float* __restrict__ yp,
    const float* __restrict__ sqp, const int* __restrict__ start,
    const int* __restrict__ cnt, float* __restrict__ S, int d) {
  const int c = blockIdx.z;
  const int n = cnt[c];
  const int by = blockIdx.y, bx = blockIdx.x;
  if (bx > by) return;
  if (by * 64 >= n) return;
  const float factor = (bx < by) ? 2.f : 1.f;
  const int base = start[c];
  __shared__ float As[BK][68];
  __shared__ float Bs2[BK][68];
  const int t = threadIdx.x;
  const int tx = t & 15, ty = t >> 4;
  const int lr = t >> 2, lk = (t & 3) * 4;
  const int arow = by * 64 + lr;
  const int brow = bx * 64 + lr;
  float acc[4][4] = {};
  for (int k0 = 0; k0 < d; k0 += BK) {
    float4 a = {0.f, 0.f, 0.f, 0.f}, b = {0.f, 0.f, 0.f, 0.f};
    if (arow < n) a = *(const float4*)(yp + (size_t)(base + arow) * d + k0 + lk);
    if (brow < n) b = *(const float4*)(yp + (size_t)(base + brow) * d + k0 + lk);
    __syncthreads();
    As[lk + 0][lr] = a.x; As[lk + 1][lr] = a.y;
    As[lk + 2][lr] = a.z; As[lk + 3][lr] = a.w;
    Bs2[lk + 0][lr] = b.x; Bs2[lk + 1][lr] = b.y;
    Bs2[lk + 2][lr] = b.z; Bs2[lk + 3][lr] = b.w;
    __syncthreads();
#pragma unroll
    for (int k = 0; k < BK; ++k) {
      float4 av = *(const float4*)&As[k][ty * 4];
      float4 bv = *(const float4*)&Bs2[k][tx * 4];
      float aa[4] = {av.x, av.y, av.z, av.w};
      float bb[4] = {bv.x, bv.y, bv.z, bv.w};
#pragma unroll
      for (int i = 0; i < 4; ++i)
#pragma unroll
        for (int j = 0; j < 4; ++j)
          acc[i][j] = fmaf(aa[i], bb[j], acc[i][j]);
    }
  }
  float sum = 0.f;
#pragma unroll
  for (int i = 0; i < 4; ++i) {
    int ri = by * 64 + ty * 4 + i;
    if (ri >= n) continue;
    float si = sqp[base + ri];
#pragma unroll
    for (int j = 0; j < 4; ++j) {
      int cj = bx * 64 + tx * 4 + j;
      if (cj >= n) continue;
      float d2 = si + sqp[base + cj] - 2.f * acc[i][j];
      d2 = fmaxf(d2, 0.f);
      sum += sqrtf(d2);
    }
  }
  __syncthreads();
  float* red = &As[0][0];
  red[t] = sum;
  __syncthreads();
  for (int s2 = 128; s2 > 0; s2 >>= 1) {
    if (t < s2) red[t] += red[t + s2];
    __syncthreads();
  }
  if (t == 0) atomicAdd(&S[c], factor * red[0]);
}

// One block per negative-sample group; pair p over g*g, 4 lanes split the dot.
__global__ __launch_bounds__(TB) void k_h1(const float* __restrict__ yh,
    const int* __restrict__ groups, float* __restrict__ h1, int g, int d) {
  const int grp = blockIdx.x;
  const int* gi = groups + grp * g;
  const int t = threadIdx.x;
  const int p = t >> 2, q = t & 3;
  const int npair = g * g;
  float d2 = 0.f;
  if (p < npair) {
    const float4* A = (const float4*)(yh + (size_t)gi[p / g] * d);
    const float4* B = (const float4*)(yh + (size_t)gi[p % g] * d);
    const int n4 = d / 4, per = n4 / 4;
    for (int k = q * per; k < (q + 1) * per; ++k) {
      float4 a = A[k], b = B[k];
      float dx = a.x - b.x, dy = a.y - b.y, dz = a.z - b.z, dw = a.w - b.w;
      d2 += dx * dx + dy * dy + dz * dz + dw * dw;
    }
  }
  d2 += __shfl_down(d2, 2, 4);
  d2 += __shfl_down(d2, 1, 4);
  float v = (q == 0 && p < npair) ? sqrtf(d2) : 0.f;
  __shared__ float red[TB];
  red[t] = v;
  __syncthreads();
  for (int s = 128; s > 0; s >>= 1) {
    if (t < s) red[t] += red[t + s];
    __syncthreads();
  }
  if (t == 0) atomicAdd(h1, red[0] / (float)npair);
}

__global__ void k_final(const float* __restrict__ C, int F,
    const float* __restrict__ S, const int* __restrict__ cnt,
    const float* __restrict__ h1, float* __restrict__ out, float beta) {
  float l1 = 0.f, l2 = 0.f;
  for (int f = 0; f < F; ++f) { float v = C[f]; l1 += fabsf(v); l2 += v * v; }
  l2 = sqrtf(l2);
  float dims = sqrtf((float)F);
  float sp = (dims - l1 / l2) / (dims - 1.f);
  float h2 = 0.f;
  for (int c = 0; c < 7; ++c) {
    if (cnt[c] > 0) { float cc = (float)cnt[c]; h2 += S[c] / (cc * cc); }
  }
  out[0] = sp + h2 - h1[0] / beta;
}

extern "C" void kernel_launch(void* const* d_in, const int* in_sizes, int n_in,
                              void* d_out, int out_size, void* d_ws, size_t ws_size,
                              hipStream_t stream) {
  const float* D = (const float*)d_in[0];
  const float* C = (const float*)d_in[1];
  const float* x = (const float*)d_in[2];
  const int* y = (const int*)d_in[3];
  const int* mask = (const int*)d_in[4];  // bool arrives widened to int32
  const int* groups = (const int*)d_in[5];
  float* out = (float*)d_out;

  const int N = in_sizes[3];            // 3000
  const int F = in_sizes[1];            // 14
  const int d = in_sizes[2] / N;        // 512
  const int G = in_sizes[5] / 7;        // 200 groups of g=7
  const int Kp = (N + 63) & ~63;        // 3008: K padded (mult of 64)

  // workspace layout
  float* ws = (float*)d_ws;
  float* yh  = ws;                          // N*d
  float* yp  = yh + (size_t)N * d;          // N*d
  float* sq  = yp + (size_t)N * d;          // N
  float* sqp = sq + N;                      // N
  float* S   = sqp + N;                     // 7 (+1 pad)
  float* h1  = S + 8;                       // 1 (+7 pad)
  int* perm   = (int*)(h1 + 8);             // N
  int* cnt    = perm + N;                   // 7 (+1)
  int* start  = cnt + 8;                    // 8
  int* cursor = start + 8;                  // 8
  short* Lb = (short*)(((uintptr_t)(cursor + 8) + 15) & ~(uintptr_t)15);  // N*Kp bf16
  short* xT = Lb + (size_t)N * Kp;          // d*Kp bf16 (offset 16B-aligned)

  k_init<<<dim3(1), TB, 0, stream>>>(S, h1, cnt);
  k_lhat<<<dim3((Kp + TB - 1) / TB, N), TB, 0, stream>>>(D, C, Lb, N, Kp, F);
  k_xT<<<dim3(d / 32, Kp / 32), dim3(32, 8), 0, stream>>>(x, xT, N, d, Kp);
  {
    int nwg = ((N + 63) / 64) * (d / 64);
    k_yhat_mfma<<<dim3(nwg), TB, 0, stream>>>(Lb, xT, x, yh, N, d, Kp);
  }
  k_sq<<<dim3((N + 3) / 4), TB, 0, stream>>>(yh, sq, N, d);
  k_count<<<dim3((N + TB - 1) / TB), TB, 0, stream>>>(y, mask, cnt, N);
  k_prefix<<<1, 1, 0, stream>>>(cnt, start, cursor);
  k_scatter<<<dim3((N + TB - 1) / TB), TB, 0, stream>>>(y, mask, cursor, perm, N);
  k_gather<<<dim3((unsigned)(((size_t)N * d + TB - 1) / TB)), TB, 0, stream>>>(
      yh, sq, perm, start, yp, sqp, d);
  k_class<<<dim3((N + 63) / 64, (N + 63) / 64, 7), TB, 0, stream>>>(
      yp, sqp, start, cnt, S, d);
  k_h1<<<dim3(G), TB, 0, stream>>>(yh, groups, h1, 7, d);
  k_final<<<1, 1, 0, stream>>>(C, F, S, cnt, h1, out, (float)G / 7.0f);
}

// Round 4
// 214.405 us; speedup vs baseline: 2.6299x; 1.5652x over previous
//
#include <hip/hip_runtime.h>
#include <math.h>
#include <stdint.h>

// DictNet: out = sparsity(C) + h2(class-pair mean dists) + h1(group mean dists)/beta
// Pipeline: sort(count/prefix/scatter/init) || Lb=bf16(D*C) || xT=bf16(x^T)
//   -> yh = x - L@x (MFMA) -> gather(perm rows -> bf16 ypb + row norms)
//   -> per-class MFMA Gram + dist sums -> group dists -> final scalar.

#define TB 256

using short8 = __attribute__((ext_vector_type(8))) short;
using f32x4  = __attribute__((ext_vector_type(4))) float;

__device__ inline short f2bf(float f) {
  union { float f; unsigned u; } v; v.f = f;
  unsigned r = v.u + 0x7FFF + ((v.u >> 16) & 1);  // RNE
  return (short)(r >> 16);
}

// count -> prefix -> scatter -> init, one block.
__global__ __launch_bounds__(1024) void k_sort(const int* __restrict__ y,
    const int* __restrict__ mask, int* __restrict__ perm, int* __restrict__ cnt,
    int* __restrict__ start, float* __restrict__ S, float* __restrict__ h1,
    int N) {
  __shared__ int lcnt[8], lcur[8], lstart[8];
  const int t = threadIdx.x;
  if (t < 8) lcnt[t] = 0;
  if (t < 7) S[t] = 0.f;
  if (t == 0) h1[0] = 0.f;
  __syncthreads();
  for (int n = t; n < N; n += 1024)
    if (mask[n] != 0) atomicAdd(&lcnt[y[n]], 1);
  __syncthreads();
  if (t == 0) {
    int s = 0;
    for (int c = 0; c < 7; ++c) { lstart[c] = s; lcur[c] = s; s += lcnt[c]; }
    lstart[7] = s;
  }
  __syncthreads();
  for (int n = t; n < N; n += 1024)
    if (mask[n] != 0) { int p = atomicAdd(&lcur[y[n]], 1); perm[p] = n; }
  if (t < 8) { start[t] = lstart[t]; cnt[t] = (t < 7) ? lcnt[t] : 0; }
}

// Lb[t] = bf16(dot(D[t,:], C)) for flat t over N*N, 2 elems/thread (112B = 7 float4).
__global__ __launch_bounds__(TB) void k_lhat(const float* __restrict__ D,
    const float* __restrict__ C, short* __restrict__ Lb, long long NP, int F) {
  __shared__ float sc[16];
  if (threadIdx.x < 14) sc[threadIdx.x] = C[threadIdx.x];
  __syncthreads();
  long long t2 = (long long)blockIdx.x * TB + threadIdx.x;
  if (t2 >= NP) return;
  const float4* p = (const float4*)(D + t2 * 28);
  float4 v0 = p[0], v1 = p[1], v2 = p[2], v3 = p[3];
  float4 v4 = p[4], v5 = p[5], v6 = p[6];
  float d0 = v0.x * sc[0];
  d0 = fmaf(v0.y, sc[1], d0);  d0 = fmaf(v0.z, sc[2], d0);
  d0 = fmaf(v0.w, sc[3], d0);  d0 = fmaf(v1.x, sc[4], d0);
  d0 = fmaf(v1.y, sc[5], d0);  d0 = fmaf(v1.z, sc[6], d0);
  d0 = fmaf(v1.w, sc[7], d0);  d0 = fmaf(v2.x, sc[8], d0);
  d0 = fmaf(v2.y, sc[9], d0);  d0 = fmaf(v2.z, sc[10], d0);
  d0 = fmaf(v2.w, sc[11], d0); d0 = fmaf(v3.x, sc[12], d0);
  d0 = fmaf(v3.y, sc[13], d0);
  float d1 = v3.z * sc[0];
  d1 = fmaf(v3.w, sc[1], d1);  d1 = fmaf(v4.x, sc[2], d1);
  d1 = fmaf(v4.y, sc[3], d1);  d1 = fmaf(v4.z, sc[4], d1);
  d1 = fmaf(v4.w, sc[5], d1);  d1 = fmaf(v5.x, sc[6], d1);
  d1 = fmaf(v5.y, sc[7], d1);  d1 = fmaf(v5.z, sc[8], d1);
  d1 = fmaf(v5.w, sc[9], d1);  d1 = fmaf(v6.x, sc[10], d1);
  d1 = fmaf(v6.y, sc[11], d1); d1 = fmaf(v6.z, sc[12], d1);
  d1 = fmaf(v6.w, sc[13], d1);
  short2 o; o.x = f2bf(d0); o.y = f2bf(d1);
  *(short2*)(Lb + t2 * 2) = o;
}

// xT[n][k] = bf16(x[k][n]), stride N. Block (32,8), 32x32 tiles.
__global__ __launch_bounds__(TB) void k_xT(const float* __restrict__ x,
    short* __restrict__ xT, int N, int d) {
  __shared__ float tile[32][33];
  const int tx = threadIdx.x, ty = threadIdx.y;
  const int r0 = blockIdx.y * 32, c0 = blockIdx.x * 32;
#pragma unroll
  for (int i = 0; i < 4; ++i) {
    int r = r0 + ty + i * 8;
    tile[ty + i * 8][tx] = (r < N) ? x[(size_t)r * d + c0 + tx] : 0.f;
  }
  __syncthreads();
  if (r0 + tx < N) {
#pragma unroll
    for (int i = 0; i < 4; ++i) {
      int c = c0 + ty + i * 8;  // output row (n)
      xT[(size_t)c * N + r0 + tx] = f2bf(tile[tx][ty + i * 8]);
    }
  }
}

// yh = x - Lb @ x via bf16 MFMA. 64x64 tile, 4 waves (2x2), each 32x32.
__global__ __launch_bounds__(TB) void k_yhat_mfma(
    const short* __restrict__ Lb, const short* __restrict__ xT,
    const float* __restrict__ x, float* __restrict__ yh, int N, int d) {
  __shared__ short As[64][40];
  __shared__ short Bs[64][40];
  const int nwg = gridDim.x;
  const int q = nwg >> 3, r = nwg & 7;
  const int xcd = blockIdx.x & 7, pos = blockIdx.x >> 3;
  const int wg = (xcd < r) ? xcd * (q + 1) + pos
                           : r * (q + 1) + (xcd - r) * q + pos;
  const int NCB = d >> 6;
  const int row0 = (wg / NCB) * 64, col0 = (wg % NCB) * 64;

  const int t = threadIdx.x;
  const int wid = t >> 6, lane = t & 63;
  const int wr = wid >> 1, wc = wid & 1;
  const int srow = t >> 2, skc = (t & 3) * 8;
  const int fr = lane & 15, fq = lane >> 4;

  const int grow = row0 + srow;
  const bool arow_ok = grow < N;
  const short* Lp = Lb + (size_t)grow * N + skc;
  const short* xp = xT + (size_t)(col0 + srow) * N + skc;

  const int KP = (N + 31) & ~31;
  f32x4 acc[2][2] = {};
  for (int k0 = 0; k0 < KP; k0 += 32) {
    const bool kok = (k0 + skc + 8 <= N);  // N%8==0: chunk all-valid or all-out
    short8 a = {0, 0, 0, 0, 0, 0, 0, 0}, b = {0, 0, 0, 0, 0, 0, 0, 0};
    if (arow_ok && kok) a = *(const short8*)(Lp + k0);
    if (kok) b = *(const short8*)(xp + k0);
    __syncthreads();
    *(short8*)&As[srow][skc] = a;
    *(short8*)&Bs[srow][skc] = b;
    __syncthreads();
    short8 af[2], bf[2];
    af[0] = *(const short8*)&As[wr * 32 + fr][fq * 8];
    af[1] = *(const short8*)&As[wr * 32 + 16 + fr][fq * 8];
    bf[0] = *(const short8*)&Bs[wc * 32 + fr][fq * 8];
    bf[1] = *(const short8*)&Bs[wc * 32 + 16 + fr][fq * 8];
#pragma unroll
    for (int mi = 0; mi < 2; ++mi)
#pragma unroll
      for (int ni = 0; ni < 2; ++ni)
        acc[mi][ni] = __builtin_amdgcn_mfma_f32_16x16x32_bf16(
            af[mi], bf[ni], acc[mi][ni], 0, 0, 0);
  }
#pragma unroll
  for (int mi = 0; mi < 2; ++mi) {
#pragma unroll
    for (int j = 0; j < 4; ++j) {
      int m = row0 + wr * 32 + mi * 16 + fq * 4 + j;
      if (m >= N) continue;
#pragma unroll
      for (int ni = 0; ni < 2; ++ni) {
        int n = col0 + wc * 32 + ni * 16 + fr;
        float v = x[(size_t)m * d + n] - acc[mi][ni][j];
        yh[(size_t)m * d + n] = v;
      }
    }
  }
}

// ypb[p,:] = bf16(yh[perm[p],:]); sqp[p] = |row|^2. One wave per row.
__global__ __launch_bounds__(TB) void k_gather(const float* __restrict__ yh,
    const int* __restrict__ perm, const int* __restrict__ start,
    short* __restrict__ ypb, float* __restrict__ sqp, int d) {
  int p = blockIdx.x * 4 + (threadIdx.x >> 6);
  if (p >= start[7]) return;
  int lane = threadIdx.x & 63;
  int src = perm[p];
  const float4* in = (const float4*)(yh + (size_t)src * d);
  float4 v1 = in[lane * 2], v2 = in[lane * 2 + 1];
  float s = v1.x * v1.x + v1.y * v1.y + v1.z * v1.z + v1.w * v1.w
          + v2.x * v2.x + v2.y * v2.y + v2.z * v2.z + v2.w * v2.w;
  short8 o;
  o[0] = f2bf(v1.x); o[1] = f2bf(v1.y); o[2] = f2bf(v1.z); o[3] = f2bf(v1.w);
  o[4] = f2bf(v2.x); o[5] = f2bf(v2.y); o[6] = f2bf(v2.z); o[7] = f2bf(v2.w);
  *(short8*)(ypb + (size_t)p * d + lane * 8) = o;
#pragma unroll
  for (int off = 32; off > 0; off >>= 1) s += __shfl_down(s, off);
  if (lane == 0) sqp[p] = s;
}

// Per-class Gram via bf16 MFMA -> distances -> sum. bx<=by, x2 off-diag.
__global__ __launch_bounds__(TB) void k_class(const short* __restrict__ ypb,
    const float* __restrict__ sqp, const int* __restrict__ start,
    const int* __restrict__ cnt, float* __restrict__ S, int d) {
  const int c = blockIdx.z;
  const int n = cnt[c];
  const int by = blockIdx.y, bx = blockIdx.x;
  if (bx > by || by * 64 >= n) return;
  const float factor = (bx < by) ? 2.f : 1.f;
  const int base = start[c];
  __shared__ short As[64][40];
  __shared__ short Bs[64][40];
  __shared__ float wred[4];
  const int t = threadIdx.x;
  const int wid = t >> 6, lane = t & 63;
  const int wr = wid >> 1, wc = wid & 1;
  const int srow = t >> 2, skc = (t & 3) * 8;
  const int fr = lane & 15, fq = lane >> 4;
  const int ar = by * 64 + srow, br = bx * 64 + srow;
  const short* Ap = ypb + (size_t)(base + ar) * d + skc;
  const short* Bp = ypb + (size_t)(base + br) * d + skc;
  f32x4 acc[2][2] = {};
  for (int k0 = 0; k0 < d; k0 += 32) {
    short8 a = {0, 0, 0, 0, 0, 0, 0, 0}, b = {0, 0, 0, 0, 0, 0, 0, 0};
    if (ar < n) a = *(const short8*)(Ap + k0);
    if (br < n) b = *(const short8*)(Bp + k0);
    __syncthreads();
    *(short8*)&As[srow][skc] = a;
    *(short8*)&Bs[srow][skc] = b;
    __syncthreads();
    short8 af[2], bf[2];
    af[0] = *(const short8*)&As[wr * 32 + fr][fq * 8];
    af[1] = *(const short8*)&As[wr * 32 + 16 + fr][fq * 8];
    bf[0] = *(const short8*)&Bs[wc * 32 + fr][fq * 8];
    bf[1] = *(const short8*)&Bs[wc * 32 + 16 + fr][fq * 8];
#pragma unroll
    for (int mi = 0; mi < 2; ++mi)
#pragma unroll
      for (int ni = 0; ni < 2; ++ni)
        acc[mi][ni] = __builtin_amdgcn_mfma_f32_16x16x32_bf16(
            af[mi], bf[ni], acc[mi][ni], 0, 0, 0);
  }
  float sum = 0.f;
#pragma unroll
  for (int mi = 0; mi < 2; ++mi) {
#pragma unroll
    for (int j = 0; j < 4; ++j) {
      int ri = by * 64 + wr * 32 + mi * 16 + fq * 4 + j;
      if (ri >= n) continue;
      float si = sqp[base + ri];
#pragma unroll
      for (int ni = 0; ni < 2; ++ni) {
        int cj = bx * 64 + wc * 32 + ni * 16 + fr;
        if (cj >= n) continue;
        float d2 = si + sqp[base + cj] - 2.f * acc[mi][ni][j];
        sum += sqrtf(fmaxf(d2, 0.f));
      }
    }
  }
#pragma unroll
  for (int off = 32; off > 0; off >>= 1) sum += __shfl_down(sum, off);
  if (lane == 0) wred[wid] = sum;
  __syncthreads();
  if (t == 0)
    atomicAdd(&S[c], factor * (wred[0] + wred[1] + wred[2] + wred[3]));
}

// One block per negative-sample group; pair p over g*g, 4 lanes split the dot.
__global__ __launch_bounds__(TB) void k_h1(const float* __restrict__ yh,
    const int* __restrict__ groups, float* __restrict__ h1, int g, int d) {
  const int grp = blockIdx.x;
  const int* gi = groups + grp * g;
  const int t = threadIdx.x;
  const int p = t >> 2, q = t & 3;
  const int npair = g * g;
  float d2 = 0.f;
  if (p < npair) {
    const float4* A = (const float4*)(yh + (size_t)gi[p / g] * d);
    const float4* B = (const float4*)(yh + (size_t)gi[p % g] * d);
    const int n4 = d / 4, per = n4 / 4;
    for (int k = q * per; k < (q + 1) * per; ++k) {
      float4 a = A[k], b = B[k];
      float dx = a.x - b.x, dy = a.y - b.y, dz = a.z - b.z, dw = a.w - b.w;
      d2 += dx * dx + dy * dy + dz * dz + dw * dw;
    }
  }
  d2 += __shfl_down(d2, 2, 4);
  d2 += __shfl_down(d2, 1, 4);
  float v = (q == 0 && p < npair) ? sqrtf(d2) : 0.f;
  __shared__ float red[TB];
  red[t] = v;
  __syncthreads();
  for (int s = 128; s > 0; s >>= 1) {
    if (t < s) red[t] += red[t + s];
    __syncthreads();
  }
  if (t == 0) atomicAdd(h1, red[0] / (float)npair);
}

__global__ void k_final(const float* __restrict__ C, int F,
    const float* __restrict__ S, const int* __restrict__ cnt,
    const float* __restrict__ h1, float* __restrict__ out, float beta) {
  float l1 = 0.f, l2 = 0.f;
  for (int f = 0; f < F; ++f) { float v = C[f]; l1 += fabsf(v); l2 += v * v; }
  l2 = sqrtf(l2);
  float dims = sqrtf((float)F);
  float sp = (dims - l1 / l2) / (dims - 1.f);
  float h2 = 0.f;
  for (int c = 0; c < 7; ++c) {
    if (cnt[c] > 0) { float cc = (float)cnt[c]; h2 += S[c] / (cc * cc); }
  }
  out[0] = sp + h2 - h1[0] / beta;
}

extern "C" void kernel_launch(void* const* d_in, const int* in_sizes, int n_in,
                              void* d_out, int out_size, void* d_ws, size_t ws_size,
                              hipStream_t stream) {
  const float* D = (const float*)d_in[0];
  const float* C = (const float*)d_in[1];
  const float* x = (const float*)d_in[2];
  const int* y = (const int*)d_in[3];
  const int* mask = (const int*)d_in[4];  // bool arrives widened to int32
  const int* groups = (const int*)d_in[5];
  float* out = (float*)d_out;

  const int N = in_sizes[3];            // 3000
  const int F = in_sizes[1];            // 14
  const int d = in_sizes[2] / N;        // 512
  const int G = in_sizes[5] / 7;        // 200 groups of g=7
  const long long NN = (long long)N * N;
  const long long NP = NN / 2;          // N even -> N*N even

  // workspace layout
  float* ws = (float*)d_ws;
  float* yh  = ws;                          // N*d
  float* sqp = yh + (size_t)N * d;          // N
  float* S   = sqp + N;                     // 8
  float* h1  = S + 8;                       // 8
  int* perm  = (int*)(h1 + 8);              // N
  int* cnt   = perm + N;                    // 8
  int* start = cnt + 8;                     // 8
  short* Lb  = (short*)(((uintptr_t)(start + 8) + 15) & ~(uintptr_t)15);  // N*N
  short* xT  = Lb + NN;                     // d*N
  short* ypb = xT + (size_t)d * N;          // N*d

  k_sort<<<dim3(1), 1024, 0, stream>>>(y, mask, perm, cnt, start, S, h1, N);
  k_lhat<<<dim3((unsigned)((NP + TB - 1) / TB)), TB, 0, stream>>>(D, C, Lb, NP, F);
  k_xT<<<dim3(d / 32, (N + 31) / 32), dim3(32, 8), 0, stream>>>(x, xT, N, d);
  {
    int nwg = ((N + 63) / 64) * (d / 64);
    k_yhat_mfma<<<dim3(nwg), TB, 0, stream>>>(Lb, xT, x, yh, N, d);
  }
  k_gather<<<dim3((N + 3) / 4), TB, 0, stream>>>(yh, perm, start, ypb, sqp, d);
  k_class<<<dim3((N + 63) / 64, (N + 63) / 64, 7), TB, 0, stream>>>(
      ypb, sqp, start, cnt, S, d);
  k_h1<<<dim3(G), TB, 0, stream>>>(yh, groups, h1, 7, d);
  k_final<<<1, 1, 0, stream>>>(C, F, S, cnt, h1, out, (float)G / 7.0f);
}

// Round 5
// 212.677 us; speedup vs baseline: 2.6513x; 1.0081x over previous
//
#include <hip/hip_runtime.h>
#include <math.h>
#include <stdint.h>

// DictNet: out = sparsity(C) + h2(class-pair mean dists) + h1(group mean dists)/beta
// 5 launches: prep(Lb=bf16(D*C) | xT=bf16(x^T) | class-sort) -> yh=x-L@x (MFMA)
//   -> gather(bf16 rows + norms) -> classh1(per-class MFMA Gram dists | h1 groups)
//   -> final scalar.

#define TB 256

using short8 = __attribute__((ext_vector_type(8))) short;
using f32x4  = __attribute__((ext_vector_type(4))) float;

__device__ inline short f2bf(float f) {
  union { float f; unsigned u; } v; v.f = f;
  unsigned r = v.u + 0x7FFF + ((v.u >> 16) & 1);  // RNE
  return (short)(r >> 16);
}

// ---- fused prep ----
// blocks [0,nbL): Lb tiles (RPB rows each, LDS-staged coalesced loads)
// blocks [nbL,nbL+nbX): xT 32x32 transpose tiles
// block nbL+nbX: class count/prefix/scatter + scalar init
__global__ __launch_bounds__(TB) void k_prep(
    const float* __restrict__ D, const float* __restrict__ Cv,
    const float* __restrict__ x, const int* __restrict__ y,
    const int* __restrict__ mask,
    short* __restrict__ Lb, short* __restrict__ xT,
    int* __restrict__ perm, int* __restrict__ cnt, int* __restrict__ start,
    float* __restrict__ S, float* __restrict__ h1,
    long long nrows, int N, int d, int F, int RPB, int nbL, int nbX) {
  __shared__ __align__(16) float lds[7168];  // 28 KB
  const int b = blockIdx.x;
  const int t = threadIdx.x;
  if (b < nbL) {
    const long long row0 = (long long)b * RPB;
    const int nrow = (int)((nrows - row0 < RPB) ? (nrows - row0) : RPB);
    const int nf4 = nrow * F / 4;  // RPB*F % 4 == 0 (RPB even, F=14)
    const float4* src = (const float4*)(D + row0 * F);
    float4* dst4 = (float4*)lds;
    for (int i = t; i < nf4; i += TB) dst4[i] = src[i];  // contiguous 4KB/wave/instr
    __syncthreads();
    if (2 * t < nrow) {
      const float* r = lds + (size_t)(2 * t) * F;
      float a0 = 0.f, a1 = 0.f;
      for (int f = 0; f < F; ++f) {
        a0 = fmaf(r[f], Cv[f], a0);
        a1 = fmaf(r[F + f], Cv[f], a1);
      }
      short2 o; o.x = f2bf(a0); o.y = f2bf(a1);
      *(short2*)(Lb + row0 + 2 * t) = o;
    }
  } else if (b < nbL + nbX) {
    const int b2 = b - nbL;
    const int nbx = d >> 5;
    const int r0 = (b2 / nbx) * 32, c0 = (b2 % nbx) * 32;
    float (*tile)[33] = (float(*)[33])lds;
    const int tx = t & 31, ty = t >> 5;  // 32 x 8
#pragma unroll
    for (int i = 0; i < 4; ++i) {
      int rr = r0 + ty + i * 8;
      tile[ty + i * 8][tx] = (rr < N) ? x[(size_t)rr * d + c0 + tx] : 0.f;
    }
    __syncthreads();
    if (r0 + tx < N) {
#pragma unroll
      for (int i = 0; i < 4; ++i) {
        int c = c0 + ty + i * 8;
        xT[(size_t)c * N + r0 + tx] = f2bf(tile[tx][ty + i * 8]);
      }
    }
  } else {
    __shared__ int lcnt[8], lcur[8], lstart[8];
    if (t < 8) lcnt[t] = 0;
    if (t < 7) S[t] = 0.f;
    if (t == 0) h1[0] = 0.f;
    __syncthreads();
    for (int n = t; n < N; n += TB)
      if (mask[n] != 0) atomicAdd(&lcnt[y[n]], 1);
    __syncthreads();
    if (t == 0) {
      int s = 0;
      for (int c = 0; c < 7; ++c) { lstart[c] = s; lcur[c] = s; s += lcnt[c]; }
      lstart[7] = s;
    }
    __syncthreads();
    for (int n = t; n < N; n += TB)
      if (mask[n] != 0) { int p = atomicAdd(&lcur[y[n]], 1); perm[p] = n; }
    if (t < 8) { start[t] = lstart[t]; cnt[t] = (t < 7) ? lcnt[t] : 0; }
  }
}

// yh = x - Lb @ x via bf16 MFMA. 64x64 tile, 4 waves (2x2), each 32x32.
__global__ __launch_bounds__(TB) void k_yhat_mfma(
    const short* __restrict__ Lb, const short* __restrict__ xT,
    const float* __restrict__ x, float* __restrict__ yh, int N, int d) {
  __shared__ short As[64][40];
  __shared__ short Bs[64][40];
  const int nwg = gridDim.x;
  const int q = nwg >> 3, r = nwg & 7;
  const int xcd = blockIdx.x & 7, pos = blockIdx.x >> 3;
  const int wg = (xcd < r) ? xcd * (q + 1) + pos
                           : r * (q + 1) + (xcd - r) * q + pos;
  const int NCB = d >> 6;
  const int row0 = (wg / NCB) * 64, col0 = (wg % NCB) * 64;

  const int t = threadIdx.x;
  const int wid = t >> 6, lane = t & 63;
  const int wr = wid >> 1, wc = wid & 1;
  const int srow = t >> 2, skc = (t & 3) * 8;
  const int fr = lane & 15, fq = lane >> 4;

  const int grow = row0 + srow;
  const bool arow_ok = grow < N;
  const short* Lp = Lb + (size_t)grow * N + skc;
  const short* xp = xT + (size_t)(col0 + srow) * N + skc;

  const int KP = (N + 31) & ~31;
  f32x4 acc[2][2] = {};
  for (int k0 = 0; k0 < KP; k0 += 32) {
    const bool kok = (k0 + skc + 8 <= N);  // N%8==0: chunk all-valid or all-out
    short8 a = {0, 0, 0, 0, 0, 0, 0, 0}, b = {0, 0, 0, 0, 0, 0, 0, 0};
    if (arow_ok && kok) a = *(const short8*)(Lp + k0);
    if (kok) b = *(const short8*)(xp + k0);
    __syncthreads();
    *(short8*)&As[srow][skc] = a;
    *(short8*)&Bs[srow][skc] = b;
    __syncthreads();
    short8 af[2], bf[2];
    af[0] = *(const short8*)&As[wr * 32 + fr][fq * 8];
    af[1] = *(const short8*)&As[wr * 32 + 16 + fr][fq * 8];
    bf[0] = *(const short8*)&Bs[wc * 32 + fr][fq * 8];
    bf[1] = *(const short8*)&Bs[wc * 32 + 16 + fr][fq * 8];
#pragma unroll
    for (int mi = 0; mi < 2; ++mi)
#pragma unroll
      for (int ni = 0; ni < 2; ++ni)
        acc[mi][ni] = __builtin_amdgcn_mfma_f32_16x16x32_bf16(
            af[mi], bf[ni], acc[mi][ni], 0, 0, 0);
  }
#pragma unroll
  for (int mi = 0; mi < 2; ++mi) {
#pragma unroll
    for (int j = 0; j < 4; ++j) {
      int m = row0 + wr * 32 + mi * 16 + fq * 4 + j;
      if (m >= N) continue;
#pragma unroll
      for (int ni = 0; ni < 2; ++ni) {
        int n = col0 + wc * 32 + ni * 16 + fr;
        float v = x[(size_t)m * d + n] - acc[mi][ni][j];
        yh[(size_t)m * d + n] = v;
      }
    }
  }
}

// ypb[p,:] = bf16(yh[perm[p],:]); sqp[p] = |row|^2. One wave per row.
__global__ __launch_bounds__(TB) void k_gather(const float* __restrict__ yh,
    const int* __restrict__ perm, const int* __restrict__ start,
    short* __restrict__ ypb, float* __restrict__ sqp, int d) {
  int p = blockIdx.x * 4 + (threadIdx.x >> 6);
  if (p >= start[7]) return;
  int lane = threadIdx.x & 63;
  int src = perm[p];
  const float4* in = (const float4*)(yh + (size_t)src * d);
  float4 v1 = in[lane * 2], v2 = in[lane * 2 + 1];
  float s = v1.x * v1.x + v1.y * v1.y + v1.z * v1.z + v1.w * v1.w
          + v2.x * v2.x + v2.y * v2.y + v2.z * v2.z + v2.w * v2.w;
  short8 o;
  o[0] = f2bf(v1.x); o[1] = f2bf(v1.y); o[2] = f2bf(v1.z); o[3] = f2bf(v1.w);
  o[4] = f2bf(v2.x); o[5] = f2bf(v2.y); o[6] = f2bf(v2.z); o[7] = f2bf(v2.w);
  *(short8*)(ypb + (size_t)p * d + lane * 8) = o;
#pragma unroll
  for (int off = 32; off > 0; off >>= 1) s += __shfl_down(s, off);
  if (lane == 0) sqp[p] = s;
}

// blockIdx.y in [0,7): per-class Gram (triangular 1D over 64-tiles) -> dist sums.
// blockIdx.y == 7: h1 negative-sample groups (first G blocks).
__global__ __launch_bounds__(TB) void k_classh1(const short* __restrict__ ypb,
    const float* __restrict__ sqp, const int* __restrict__ start,
    const int* __restrict__ cnt, const float* __restrict__ yh,
    const int* __restrict__ groups, float* __restrict__ S,
    float* __restrict__ h1, int d, int G) {
  __shared__ short As[64][40];
  __shared__ short Bs[64][40];
  __shared__ float wred[4];
  const int t = threadIdx.x;
  const int z = blockIdx.y;

  if (z == 7) {  // ---- h1 ----
    if (blockIdx.x >= G) return;
    const int g = 7;
    const int* gi = groups + blockIdx.x * g;
    const int p = t >> 2, qq = t & 3;
    const int npair = g * g;
    float d2 = 0.f;
    if (p < npair) {
      const float4* A = (const float4*)(yh + (size_t)gi[p / g] * d);
      const float4* B = (const float4*)(yh + (size_t)gi[p % g] * d);
      const int per = (d / 4) / 4;
      for (int k = qq * per; k < (qq + 1) * per; ++k) {
        float4 a = A[k], b = B[k];
        float dx = a.x - b.x, dy = a.y - b.y, dz = a.z - b.z, dw = a.w - b.w;
        d2 += dx * dx + dy * dy + dz * dz + dw * dw;
      }
    }
    d2 += __shfl_down(d2, 2, 4);
    d2 += __shfl_down(d2, 1, 4);
    float v = (qq == 0 && p < npair) ? sqrtf(d2) : 0.f;
    float* red = (float*)As;
    red[t] = v;
    __syncthreads();
    for (int s = 128; s > 0; s >>= 1) {
      if (t < s) red[t] += red[t + s];
      __syncthreads();
    }
    if (t == 0) atomicAdd(h1, red[0] / (float)npair);
    return;
  }

  // ---- per-class Gram ----
  const int c = z;
  const int n = cnt[c];
  int k = blockIdx.x;  // triangular decode: k -> (by, bx), bx <= by
  int by = (int)((sqrtf(8.f * (float)k + 1.f) - 1.f) * 0.5f);
  while ((by + 1) * (by + 2) / 2 <= k) ++by;
  while (by * (by + 1) / 2 > k) --by;
  const int bx = k - by * (by + 1) / 2;
  if (by * 64 >= n) return;
  const float factor = (bx < by) ? 2.f : 1.f;
  const int base = start[c];
  const int wid = t >> 6, lane = t & 63;
  const int wr = wid >> 1, wc = wid & 1;
  const int srow = t >> 2, skc = (t & 3) * 8;
  const int fr = lane & 15, fq = lane >> 4;
  const int ar = by * 64 + srow, br = bx * 64 + srow;
  const short* Ap = ypb + (size_t)(base + ar) * d + skc;
  const short* Bp = ypb + (size_t)(base + br) * d + skc;
  f32x4 acc[2][2] = {};
  for (int k0 = 0; k0 < d; k0 += 32) {
    short8 a = {0, 0, 0, 0, 0, 0, 0, 0}, b = {0, 0, 0, 0, 0, 0, 0, 0};
    if (ar < n) a = *(const short8*)(Ap + k0);
    if (br < n) b = *(const short8*)(Bp + k0);
    __syncthreads();
    *(short8*)&As[srow][skc] = a;
    *(short8*)&Bs[srow][skc] = b;
    __syncthreads();
    short8 af[2], bf[2];
    af[0] = *(const short8*)&As[wr * 32 + fr][fq * 8];
    af[1] = *(const short8*)&As[wr * 32 + 16 + fr][fq * 8];
    bf[0] = *(const short8*)&Bs[wc * 32 + fr][fq * 8];
    bf[1] = *(const short8*)&Bs[wc * 32 + 16 + fr][fq * 8];
#pragma unroll
    for (int mi = 0; mi < 2; ++mi)
#pragma unroll
      for (int ni = 0; ni < 2; ++ni)
        acc[mi][ni] = __builtin_amdgcn_mfma_f32_16x16x32_bf16(
            af[mi], bf[ni], acc[mi][ni], 0, 0, 0);
  }
  float sum = 0.f;
#pragma unroll
  for (int mi = 0; mi < 2; ++mi) {
#pragma unroll
    for (int j = 0; j < 4; ++j) {
      int ri = by * 64 + wr * 32 + mi * 16 + fq * 4 + j;
      if (ri >= n) continue;
      float si = sqp[base + ri];
#pragma unroll
      for (int ni = 0; ni < 2; ++ni) {
        int cj = bx * 64 + wc * 32 + ni * 16 + fr;
        if (cj >= n) continue;
        float d2 = si + sqp[base + cj] - 2.f * acc[mi][ni][j];
        sum += sqrtf(fmaxf(d2, 0.f));
      }
    }
  }
#pragma unroll
  for (int off = 32; off > 0; off >>= 1) sum += __shfl_down(sum, off);
  if (lane == 0) wred[wid] = sum;
  __syncthreads();
  if (t == 0)
    atomicAdd(&S[c], factor * (wred[0] + wred[1] + wred[2] + wred[3]));
}

__global__ void k_final(const float* __restrict__ C, int F,
    const float* __restrict__ S, const int* __restrict__ cnt,
    const float* __restrict__ h1, float* __restrict__ out, float beta) {
  float l1 = 0.f, l2 = 0.f;
  for (int f = 0; f < F; ++f) { float v = C[f]; l1 += fabsf(v); l2 += v * v; }
  l2 = sqrtf(l2);
  float dims = sqrtf((float)F);
  float sp = (dims - l1 / l2) / (dims - 1.f);
  float h2 = 0.f;
  for (int c = 0; c < 7; ++c) {
    if (cnt[c] > 0) { float cc = (float)cnt[c]; h2 += S[c] / (cc * cc); }
  }
  out[0] = sp + h2 - h1[0] / beta;
}

extern "C" void kernel_launch(void* const* d_in, const int* in_sizes, int n_in,
                              void* d_out, int out_size, void* d_ws, size_t ws_size,
                              hipStream_t stream) {
  const float* D = (const float*)d_in[0];
  const float* C = (const float*)d_in[1];
  const float* x = (const float*)d_in[2];
  const int* y = (const int*)d_in[3];
  const int* mask = (const int*)d_in[4];  // bool arrives widened to int32
  const int* groups = (const int*)d_in[5];
  float* out = (float*)d_out;

  const int N = in_sizes[3];            // 3000
  const int F = in_sizes[1];            // 14
  const int d = in_sizes[2] / N;        // 512
  const int G = in_sizes[5] / 7;        // 200 groups of g=7
  const long long NN = (long long)N * N;

  // workspace layout
  float* ws = (float*)d_ws;
  float* yh  = ws;                          // N*d
  float* sqp = yh + (size_t)N * d;          // N
  float* S   = sqp + N;                     // 8
  float* h1  = S + 8;                       // 8
  int* perm  = (int*)(h1 + 8);              // N
  int* cnt   = perm + N;                    // 8
  int* start = cnt + 8;                     // 8
  short* Lb  = (short*)(((uintptr_t)(start + 8) + 15) & ~(uintptr_t)15);  // N*N
  short* xT  = Lb + NN;                     // d*N
  short* ypb = xT + (size_t)d * N;          // N*d

  const int RPB = (7168 / F) & ~1;          // rows per Lb tile (512 @ F=14)
  const int nbL = (int)((NN + RPB - 1) / RPB);
  const int nbX = (d / 32) * ((N + 31) / 32);
  k_prep<<<dim3(nbL + nbX + 1), TB, 0, stream>>>(
      D, C, x, y, mask, Lb, xT, perm, cnt, start, S, h1, NN, N, d, F, RPB,
      nbL, nbX);
  {
    int nwg = ((N + 63) / 64) * (d / 64);
    k_yhat_mfma<<<dim3(nwg), TB, 0, stream>>>(Lb, xT, x, yh, N, d);
  }
  k_gather<<<dim3((N + 3) / 4), TB, 0, stream>>>(yh, perm, start, ypb, sqp, d);
  {
    int NB = (N + 63) / 64;
    int nbT = NB * (NB + 1) / 2;
    if (nbT < G) nbT = G;
    k_classh1<<<dim3(nbT, 8), TB, 0, stream>>>(ypb, sqp, start, cnt, yh,
                                               groups, S, h1, d, G);
  }
  k_final<<<1, 1, 0, stream>>>(C, F, S, cnt, h1, out, (float)G / 7.0f);
}

// Round 6
// 181.688 us; speedup vs baseline: 3.1035x; 1.1706x over previous
//
#include <hip/hip_runtime.h>
#include <math.h>
#include <stdint.h>

// DictNet: out = sparsity(C) + h2(class-pair mean dists) + h1(group mean dists)/beta
// 5 launches: prep(Lb=bf16(D*C) | xT=bf16(x^T) | sort+tile-prefix) -> yh=x-L@x (MFMA,
//   BK=64, reg-prefetch) -> gather(bf16 rows + norms) -> classh1(1D grid: h1 groups +
//   per-class MFMA Gram dists via device tile prefix) -> final scalar.

#define TB 256

using short8 = __attribute__((ext_vector_type(8))) short;
using f32x4  = __attribute__((ext_vector_type(4))) float;

__device__ inline short f2bf(float f) {
  union { float f; unsigned u; } v; v.f = f;
  unsigned r = v.u + 0x7FFF + ((v.u >> 16) & 1);  // RNE
  return (short)(r >> 16);
}

// ---- fused prep ----
// blocks [0,nbL): Lb tiles (RPB rows, LDS-staged; full tiles use unrolled 7-load MLP)
// blocks [nbL,nbL+nbX): xT 32x32 transpose tiles
// block nbL+nbX: class count/prefix/scatter + triangular-tile prefix + scalar init
__global__ __launch_bounds__(TB) void k_prep(
    const float* __restrict__ D, const float* __restrict__ Cv,
    const float* __restrict__ x, const int* __restrict__ y,
    const int* __restrict__ mask,
    short* __restrict__ Lb, short* __restrict__ xT,
    int* __restrict__ perm, int* __restrict__ cnt, int* __restrict__ start,
    int* __restrict__ tstart, float* __restrict__ S, float* __restrict__ h1,
    long long nrows, int N, int d, int F, int RPB, int nbL, int nbX) {
  __shared__ __align__(16) float lds[7168];  // 28 KB
  const int b = blockIdx.x;
  const int t = threadIdx.x;
  if (b < nbL) {
    const long long row0 = (long long)b * RPB;
    const int nrow = (int)((nrows - row0 < RPB) ? (nrows - row0) : RPB);
    const float4* src = (const float4*)(D + row0 * F);
    float4* dst4 = (float4*)lds;
    if (nrow == RPB) {  // RPB*F/4 == 7*TB: 7 independent loads -> 7 KB/wave in flight
#pragma unroll
      for (int u = 0; u < 7; ++u) dst4[t + u * TB] = src[t + u * TB];
    } else {
      const int nf4 = nrow * F / 4;  // nrow even, F=14 -> mult of 4
      for (int i = t; i < nf4; i += TB) dst4[i] = src[i];
    }
    __syncthreads();
    if (2 * t < nrow) {
      const float* r = lds + (size_t)(2 * t) * F;
      float a0 = 0.f, a1 = 0.f;
      for (int f = 0; f < F; ++f) {
        a0 = fmaf(r[f], Cv[f], a0);
        a1 = fmaf(r[F + f], Cv[f], a1);
      }
      short2 o; o.x = f2bf(a0); o.y = f2bf(a1);
      *(short2*)(Lb + row0 + 2 * t) = o;
    }
  } else if (b < nbL + nbX) {
    const int b2 = b - nbL;
    const int nbx = d >> 5;
    const int r0 = (b2 / nbx) * 32, c0 = (b2 % nbx) * 32;
    float (*tile)[33] = (float(*)[33])lds;
    const int tx = t & 31, ty = t >> 5;  // 32 x 8
#pragma unroll
    for (int i = 0; i < 4; ++i) {
      int rr = r0 + ty + i * 8;
      tile[ty + i * 8][tx] = (rr < N) ? x[(size_t)rr * d + c0 + tx] : 0.f;
    }
    __syncthreads();
    if (r0 + tx < N) {
#pragma unroll
      for (int i = 0; i < 4; ++i) {
        int c = c0 + ty + i * 8;
        xT[(size_t)c * N + r0 + tx] = f2bf(tile[tx][ty + i * 8]);
      }
    }
  } else {
    __shared__ int lcnt[8], lcur[8], lstart[8], ltile[8];
    if (t < 8) lcnt[t] = 0;
    if (t < 7) S[t] = 0.f;
    if (t == 0) h1[0] = 0.f;
    __syncthreads();
    for (int n = t; n < N; n += TB)
      if (mask[n] != 0) atomicAdd(&lcnt[y[n]], 1);
    __syncthreads();
    if (t == 0) {
      int s = 0;
      for (int c = 0; c < 7; ++c) { lstart[c] = s; lcur[c] = s; s += lcnt[c]; }
      lstart[7] = s;
      int tt = 0;
      for (int c = 0; c < 7; ++c) {
        int nb = (lcnt[c] + 63) >> 6;
        ltile[c] = tt; tt += nb * (nb + 1) / 2;
      }
      ltile[7] = tt;
    }
    __syncthreads();
    for (int n = t; n < N; n += TB)
      if (mask[n] != 0) { int p = atomicAdd(&lcur[y[n]], 1); perm[p] = n; }
    if (t < 8) {
      start[t] = lstart[t];
      cnt[t] = (t < 7) ? lcnt[t] : 0;
      tstart[t] = ltile[t];
    }
  }
}

// yh = x - Lb @ x via bf16 MFMA. 64x64 tile, BK=64 (2 halves), register prefetch:
// next tile's loads issue before the barrier, stay in flight through the MFMAs.
__global__ __launch_bounds__(TB) void k_yhat_mfma(
    const short* __restrict__ Lb, const short* __restrict__ xT,
    const float* __restrict__ x, float* __restrict__ yh, int N, int d) {
  __shared__ short As[2][64][40];
  __shared__ short Bs[2][64][40];
  const int nwg = gridDim.x;
  const int q = nwg >> 3, r = nwg & 7;
  const int xcd = blockIdx.x & 7, pos = blockIdx.x >> 3;
  const int wg = (xcd < r) ? xcd * (q + 1) + pos
                           : r * (q + 1) + (xcd - r) * q + pos;
  const int NCB = d >> 6;
  const int row0 = (wg / NCB) * 64, col0 = (wg % NCB) * 64;

  const int t = threadIdx.x;
  const int wid = t >> 6, lane = t & 63;
  const int wr = wid >> 1, wc = wid & 1;
  const int srow = t >> 2, skc = (t & 3) * 8;
  const int fr = lane & 15, fq = lane >> 4;

  const int grow = row0 + srow;
  const bool arow_ok = grow < N;
  const short* Lp = Lb + (size_t)grow * N + skc;
  const short* xp = xT + (size_t)(col0 + srow) * N + skc;

  const short8 z8 = {0, 0, 0, 0, 0, 0, 0, 0};
  const int KP = (N + 63) & ~63;

  short8 ca[2], cb[2];
#pragma unroll
  for (int h = 0; h < 2; ++h) {
    int k = h * 32;
    bool kok = (k + skc + 8 <= N);  // N%8==0: chunk all-valid or all-out
    ca[h] = (arow_ok && kok) ? *(const short8*)(Lp + k) : z8;
    cb[h] = kok ? *(const short8*)(xp + k) : z8;
  }

  f32x4 acc[2][2] = {};
  for (int k0 = 0; k0 < KP; k0 += 64) {
    short8 na[2] = {z8, z8}, nb[2] = {z8, z8};
    const int k1 = k0 + 64;
    if (k1 < KP) {
#pragma unroll
      for (int h = 0; h < 2; ++h) {
        int k = k1 + h * 32;
        bool kok = (k + skc + 8 <= N);
        if (arow_ok && kok) na[h] = *(const short8*)(Lp + k);
        if (kok) nb[h] = *(const short8*)(xp + k);
      }
    }
    __syncthreads();
    *(short8*)&As[0][srow][skc] = ca[0];
    *(short8*)&As[1][srow][skc] = ca[1];
    *(short8*)&Bs[0][srow][skc] = cb[0];
    *(short8*)&Bs[1][srow][skc] = cb[1];
    __syncthreads();
#pragma unroll
    for (int h = 0; h < 2; ++h) {
      short8 af[2], bf[2];
      af[0] = *(const short8*)&As[h][wr * 32 + fr][fq * 8];
      af[1] = *(const short8*)&As[h][wr * 32 + 16 + fr][fq * 8];
      bf[0] = *(const short8*)&Bs[h][wc * 32 + fr][fq * 8];
      bf[1] = *(const short8*)&Bs[h][wc * 32 + 16 + fr][fq * 8];
#pragma unroll
      for (int mi = 0; mi < 2; ++mi)
#pragma unroll
        for (int ni = 0; ni < 2; ++ni)
          acc[mi][ni] = __builtin_amdgcn_mfma_f32_16x16x32_bf16(
              af[mi], bf[ni], acc[mi][ni], 0, 0, 0);
    }
    ca[0] = na[0]; ca[1] = na[1]; cb[0] = nb[0]; cb[1] = nb[1];
  }
#pragma unroll
  for (int mi = 0; mi < 2; ++mi) {
#pragma unroll
    for (int j = 0; j < 4; ++j) {
      int m = row0 + wr * 32 + mi * 16 + fq * 4 + j;
      if (m >= N) continue;
#pragma unroll
      for (int ni = 0; ni < 2; ++ni) {
        int n = col0 + wc * 32 + ni * 16 + fr;
        float v = x[(size_t)m * d + n] - acc[mi][ni][j];
        yh[(size_t)m * d + n] = v;
      }
    }
  }
}

// ypb[p,:] = bf16(yh[perm[p],:]); sqp[p] = |row|^2. One wave per row.
__global__ __launch_bounds__(TB) void k_gather(const float* __restrict__ yh,
    const int* __restrict__ perm, const int* __restrict__ start,
    short* __restrict__ ypb, float* __restrict__ sqp, int d) {
  int p = blockIdx.x * 4 + (threadIdx.x >> 6);
  if (p >= start[7]) return;
  int lane = threadIdx.x & 63;
  int src = perm[p];
  const float4* in = (const float4*)(yh + (size_t)src * d);
  float4 v1 = in[lane * 2], v2 = in[lane * 2 + 1];
  float s = v1.x * v1.x + v1.y * v1.y + v1.z * v1.z + v1.w * v1.w
          + v2.x * v2.x + v2.y * v2.y + v2.z * v2.z + v2.w * v2.w;
  short8 o;
  o[0] = f2bf(v1.x); o[1] = f2bf(v1.y); o[2] = f2bf(v1.z); o[3] = f2bf(v1.w);
  o[4] = f2bf(v2.x); o[5] = f2bf(v2.y); o[6] = f2bf(v2.z); o[7] = f2bf(v2.w);
  *(short8*)(ypb + (size_t)p * d + lane * 8) = o;
#pragma unroll
  for (int off = 32; off > 0; off >>= 1) s += __shfl_down(s, off);
  if (lane == 0) sqp[p] = s;
}

// 1D grid: blocks [0,G) = h1 groups; blocks [G, G+tri(NB)) = class Gram tiles,
// mapped via device-computed triangular-tile prefix (tstart). BK=64 + prefetch.
__global__ __launch_bounds__(TB) void k_classh1(const short* __restrict__ ypb,
    const float* __restrict__ sqp, const int* __restrict__ start,
    const int* __restrict__ cnt, const int* __restrict__ tstart,
    const float* __restrict__ yh, const int* __restrict__ groups,
    float* __restrict__ S, float* __restrict__ h1, int d, int G) {
  __shared__ short As[2][64][40];
  __shared__ short Bs[2][64][40];
  __shared__ float wred[4];
  __shared__ float red[TB];
  const int t = threadIdx.x;
  const int b = blockIdx.x;

  if (b < G) {  // ---- h1 ----
    const int g = 7;
    const int* gi = groups + b * g;
    const int p = t >> 2, qq = t & 3;
    const int npair = g * g;
    float d2 = 0.f;
    if (p < npair) {
      const float4* A = (const float4*)(yh + (size_t)gi[p / g] * d);
      const float4* B = (const float4*)(yh + (size_t)gi[p % g] * d);
      const int per = (d / 4) / 4;
      for (int k = qq * per; k < (qq + 1) * per; ++k) {
        float4 a = A[k], b2 = B[k];
        float dx = a.x - b2.x, dy = a.y - b2.y, dz = a.z - b2.z, dw = a.w - b2.w;
        d2 += dx * dx + dy * dy + dz * dz + dw * dw;
      }
    }
    d2 += __shfl_down(d2, 2, 4);
    d2 += __shfl_down(d2, 1, 4);
    float v = (qq == 0 && p < npair) ? sqrtf(d2) : 0.f;
    red[t] = v;
    __syncthreads();
    for (int s = 128; s > 0; s >>= 1) {
      if (t < s) red[t] += red[t + s];
      __syncthreads();
    }
    if (t == 0) atomicAdd(h1, red[0] / (float)npair);
    return;
  }

  // ---- per-class Gram tile ----
  const int w = b - G;
  if (w >= tstart[7]) return;
  int c = 0;
  while (c < 6 && w >= tstart[c + 1]) ++c;
  const int n = cnt[c];
  const int base = start[c];
  const int k = w - tstart[c];
  int by = (int)((sqrtf(8.f * (float)k + 1.f) - 1.f) * 0.5f);
  while ((by + 1) * (by + 2) / 2 <= k) ++by;
  while (by * (by + 1) / 2 > k) --by;
  const int bx = k - by * (by + 1) / 2;
  const float factor = (bx < by) ? 2.f : 1.f;

  const int wid = t >> 6, lane = t & 63;
  const int wr = wid >> 1, wc = wid & 1;
  const int srow = t >> 2, skc = (t & 3) * 8;
  const int fr = lane & 15, fq = lane >> 4;
  const int ar = by * 64 + srow, br = bx * 64 + srow;
  const short* Ap = ypb + (size_t)(base + ar) * d + skc;
  const short* Bp = ypb + (size_t)(base + br) * d + skc;
  const short8 z8 = {0, 0, 0, 0, 0, 0, 0, 0};

  short8 ca[2], cb[2];
#pragma unroll
  for (int h = 0; h < 2; ++h) {
    ca[h] = (ar < n) ? *(const short8*)(Ap + h * 32) : z8;
    cb[h] = (br < n) ? *(const short8*)(Bp + h * 32) : z8;
  }
  f32x4 acc[2][2] = {};
  for (int k0 = 0; k0 < d; k0 += 64) {  // d % 64 == 0
    short8 na[2] = {z8, z8}, nb[2] = {z8, z8};
    const int k1 = k0 + 64;
    if (k1 < d) {
#pragma unroll
      for (int h = 0; h < 2; ++h) {
        if (ar < n) na[h] = *(const short8*)(Ap + k1 + h * 32);
        if (br < n) nb[h] = *(const short8*)(Bp + k1 + h * 32);
      }
    }
    __syncthreads();
    *(short8*)&As[0][srow][skc] = ca[0];
    *(short8*)&As[1][srow][skc] = ca[1];
    *(short8*)&Bs[0][srow][skc] = cb[0];
    *(short8*)&Bs[1][srow][skc] = cb[1];
    __syncthreads();
#pragma unroll
    for (int h = 0; h < 2; ++h) {
      short8 af[2], bf[2];
      af[0] = *(const short8*)&As[h][wr * 32 + fr][fq * 8];
      af[1] = *(const short8*)&As[h][wr * 32 + 16 + fr][fq * 8];
      bf[0] = *(const short8*)&Bs[h][wc * 32 + fr][fq * 8];
      bf[1] = *(const short8*)&Bs[h][wc * 32 + 16 + fr][fq * 8];
#pragma unroll
      for (int mi = 0; mi < 2; ++mi)
#pragma unroll
        for (int ni = 0; ni < 2; ++ni)
          acc[mi][ni] = __builtin_amdgcn_mfma_f32_16x16x32_bf16(
              af[mi], bf[ni], acc[mi][ni], 0, 0, 0);
    }
    ca[0] = na[0]; ca[1] = na[1]; cb[0] = nb[0]; cb[1] = nb[1];
  }
  float sum = 0.f;
#pragma unroll
  for (int mi = 0; mi < 2; ++mi) {
#pragma unroll
    for (int j = 0; j < 4; ++j) {
      int ri = by * 64 + wr * 32 + mi * 16 + fq * 4 + j;
      if (ri >= n) continue;
      float si = sqp[base + ri];
#pragma unroll
      for (int ni = 0; ni < 2; ++ni) {
        int cj = bx * 64 + wc * 32 + ni * 16 + fr;
        if (cj >= n) continue;
        float d2 = si + sqp[base + cj] - 2.f * acc[mi][ni][j];
        sum += sqrtf(fmaxf(d2, 0.f));
      }
    }
  }
#pragma unroll
  for (int off = 32; off > 0; off >>= 1) sum += __shfl_down(sum, off);
  if (lane == 0) wred[wid] = sum;
  __syncthreads();
  if (t == 0)
    atomicAdd(&S[c], factor * (wred[0] + wred[1] + wred[2] + wred[3]));
}

__global__ void k_final(const float* __restrict__ C, int F,
    const float* __restrict__ S, const int* __restrict__ cnt,
    const float* __restrict__ h1, float* __restrict__ out, float beta) {
  float l1 = 0.f, l2 = 0.f;
  for (int f = 0; f < F; ++f) { float v = C[f]; l1 += fabsf(v); l2 += v * v; }
  l2 = sqrtf(l2);
  float dims = sqrtf((float)F);
  float sp = (dims - l1 / l2) / (dims - 1.f);
  float h2 = 0.f;
  for (int c = 0; c < 7; ++c) {
    if (cnt[c] > 0) { float cc = (float)cnt[c]; h2 += S[c] / (cc * cc); }
  }
  out[0] = sp + h2 - h1[0] / beta;
}

extern "C" void kernel_launch(void* const* d_in, const int* in_sizes, int n_in,
                              void* d_out, int out_size, void* d_ws, size_t ws_size,
                              hipStream_t stream) {
  const float* D = (const float*)d_in[0];
  const float* C = (const float*)d_in[1];
  const float* x = (const float*)d_in[2];
  const int* y = (const int*)d_in[3];
  const int* mask = (const int*)d_in[4];  // bool arrives widened to int32
  const int* groups = (const int*)d_in[5];
  float* out = (float*)d_out;

  const int N = in_sizes[3];            // 3000
  const int F = in_sizes[1];            // 14
  const int d = in_sizes[2] / N;        // 512
  const int G = in_sizes[5] / 7;        // 200 groups of g=7
  const long long NN = (long long)N * N;

  // workspace layout
  float* ws = (float*)d_ws;
  float* yh  = ws;                          // N*d
  float* sqp = yh + (size_t)N * d;          // N
  float* S   = sqp + N;                     // 8
  float* h1  = S + 8;                       // 8
  int* perm   = (int*)(h1 + 8);             // N
  int* cnt    = perm + N;                   // 8
  int* start  = cnt + 8;                    // 8
  int* tstart = start + 8;                  // 8
  short* Lb  = (short*)(((uintptr_t)(tstart + 8) + 15) & ~(uintptr_t)15);  // N*N
  short* xT  = Lb + NN;                     // d*N
  short* ypb = xT + (size_t)d * N;          // N*d

  const int RPB = (7168 / F) & ~1;          // rows per Lb tile (512 @ F=14)
  const int nbL = (int)((NN + RPB - 1) / RPB);
  const int nbX = (d / 32) * ((N + 31) / 32);
  k_prep<<<dim3(nbL + nbX + 1), TB, 0, stream>>>(
      D, C, x, y, mask, Lb, xT, perm, cnt, start, tstart, S, h1, NN, N, d, F,
      RPB, nbL, nbX);
  {
    int nwg = ((N + 63) / 64) * (d / 64);
    k_yhat_mfma<<<dim3(nwg), TB, 0, stream>>>(Lb, xT, x, yh, N, d);
  }
  k_gather<<<dim3((N + 3) / 4), TB, 0, stream>>>(yh, perm, start, ypb, sqp, d);
  {
    int NB = (N + 63) / 64;
    int nbT = NB * (NB + 1) / 2;  // worst case: all rows in one class
    k_classh1<<<dim3(G + nbT), TB, 0, stream>>>(ypb, sqp, start, cnt, tstart,
                                                yh, groups, S, h1, d, G);
  }
  k_final<<<1, 1, 0, stream>>>(C, F, S, cnt, h1, out, (float)G / 7.0f);
}